// Round 13
// baseline (170.946 us; speedup 1.0000x reference)
//
#include <hip/hip_runtime.h>
#include <cfloat>

#define NB 4
#define NN 4096
#define NC 256

typedef _Float16 f16;
typedef _Float16 f16x8 __attribute__((ext_vector_type(8)));
typedef float f32x4 __attribute__((ext_vector_type(4)));

__device__ __forceinline__ void gl_lds16(const void* g, void* l) {
    __builtin_amdgcn_global_load_lds(
        (const __attribute__((address_space(1))) unsigned int*)g,
        (__attribute__((address_space(3))) unsigned int*)l, 16, 0, 0);
}

// ---------------- prep: fp32 -> f16 hi/lo split + diag ----------------
__global__ __launch_bounds__(256) void prep_kernel(const float* __restrict__ x,
                                                   f16* __restrict__ xh,
                                                   f16* __restrict__ xl,
                                                   float* __restrict__ diag) {
    const int lane = threadIdx.x & 63;
    const int wave = threadIdx.x >> 6;
    const int row  = (blockIdx.x << 2) + wave;            // 0..16383
    const float4 v = ((const float4*)(x + (size_t)row * NC))[lane];
    union { f16 h[4]; uint2 u; } H, L;
    float vv[4] = {v.x, v.y, v.z, v.w};
    float s = 0.f;
    #pragma unroll
    for (int k = 0; k < 4; ++k) {
        H.h[k] = (f16)vv[k];
        L.h[k] = (f16)(vv[k] - (float)H.h[k]);
        s = fmaf(vv[k], vv[k], s);
    }
    *(uint2*)(xh + (size_t)row * NC + lane * 4) = H.u;
    *(uint2*)(xl + (size_t)row * NC + lane * 4) = L.u;
    #pragma unroll
    for (int off = 32; off; off >>= 1) s += __shfl_xor(s, off, 64);
    if (lane == 0) diag[row] = s;
}

// ---------------- main MFMA kernel ----------------
// r13 = r4 geometry (8 waves, TJ=512, wave-PRIVATE single-buffered stripes,
// barrier-free, vmcnt(0) stripe guard — passed @106us) + r8 in-wave A-frag
// pipelining (passed @107us) + __launch_bounds__(512, 1).
// KEY: (512,1) gives 2 waves/SIMD residency (block shape forces it) with a
// 256-VGPR/wave allocator budget (2x256 = the full 512-reg SIMD file), so
// the r8 register pipeline FITS at 2 waves/SIMD — r5's spill was the
// (512,2) 128-cap, not the wave count. With 2 independent (barrier-free,
// wave-private-stripe) waves per SIMD, m114-style MFMA/VALU cross-wave
// co-scheduling can hide each wave's reads+VALU+waits under the other
// wave's MFMA phase — attacking the additive wall (MFMA 931 + rest ~1070
// per chunk) that held across r4/r8/r10/r12 at 1 effective phase per SIMD.
// setprio(1) wraps the MFMA block (T5's regime: multi-wave, NOT lockstep).
// Dead ends (do not revisit): A-in-registers (arch cap 256: r5/r9),
// read-spreading+vmcnt-at-top (r10 -10%), B-direct-from-global (r11 -35%),
// barrier-per-chunk lockstep (r0-r3), inter-quarter SB removal (r12 ~flat).
#define TI 64
#define TJ 512
#define KCB 32
#define NCHUNK (NC / KCB)    // 8 k-chunks per j-tile
#define NJT (NN / TJ)        // 8 j-tiles

#define TRIPLE(RT, CT, AH, AL, BH, BL) \
    acc[RT][CT] = __builtin_amdgcn_mfma_f32_16x16x32_f16(AH, BH[CT], acc[RT][CT], 0, 0, 0); \
    acc[RT][CT] = __builtin_amdgcn_mfma_f32_16x16x32_f16(AH, BL[CT], acc[RT][CT], 0, 0, 0); \
    acc[RT][CT] = __builtin_amdgcn_mfma_f32_16x16x32_f16(AL, BH[CT], acc[RT][CT], 0, 0, 0);

#define QUARTER(RT, AH, AL, BH, BL) \
    TRIPLE(RT, 0, AH, AL, BH, BL) TRIPLE(RT, 1, AH, AL, BH, BL) \
    TRIPLE(RT, 2, AH, AL, BH, BL) TRIPLE(RT, 3, AH, AL, BH, BL)

// A-frag read for k-chunk KN, row-block RT, into named regs (Ah layout:
// slot g holds granule g ^ (row&7))
#define RDA(DH, DL, RT, KN) \
    DH = *(const f16x8*)&Ah[((RT) * 16 + l15) * NC + ((((KN) * 4 + quad) ^ sw) * 8)]; \
    DL = *(const f16x8*)&Al[((RT) * 16 + l15) * NC + ((((KN) * 4 + quad) ^ sw) * 8)];

#define SB __builtin_amdgcn_sched_barrier(0)

// One k-chunk (KC literal 0..7). A frags for chunk KC were ds_read during
// chunk KC-1's quarters (drained by this chunk's lgkmcnt(0)). Stripe is
// wave-private single-buffer: vmcnt(0) at top = my DMA (issued a full chunk
// ago, covered by ~931 cyc of my own MFMAs) landed; bf reads; lgkmcnt(0) =
// bf in regs -> stripe free; issue next chunk's DMA; MFMA quarters with
// next-chunk A reads interleaved (a3 ping-pongs for the Q3 WAR).
#define CHUNK(KC, A3HC, A3LC, A3HN, A3LN) do { \
    asm volatile("s_waitcnt vmcnt(0)" ::: "memory"); \
    SB; \
    _Pragma("unroll") \
    for (int ct = 0; ct < 4; ++ct) { \
        const int c = ct * 16 + l15; \
        bfh[ct] = *(const f16x8*)&swh[c * KCB + gB]; \
        bfl[ct] = *(const f16x8*)&swl[c * KCB + gB]; \
    } \
    asm volatile("s_waitcnt lgkmcnt(0)" ::: "memory"); \
    SB; \
    { \
        const int jn = ((KC) == 7) ? jt + 1 : jt; \
        if (jn < NJT) { \
            const size_t base = (size_t)(jn * TJ + w * 64) * NC + (size_t)((((KC) + 1) & 7) * KCB); \
            _Pragma("unroll") \
            for (int t = 0; t < 4; ++t) { \
                const size_t goff = base + (size_t)(t * 16 + bcol) * NC + bslot * 8; \
                gl_lds16(xhb + goff, swh + t * 512); \
                gl_lds16(xlb + goff, swl + t * 512); \
            } \
        } \
    } \
    SB; \
    __builtin_amdgcn_s_setprio(1); \
    QUARTER(0, a0h, a0l, bfh, bfl) \
    RDA(a0h, a0l, 0, ((KC) + 1) & 7) \
    QUARTER(1, a1h, a1l, bfh, bfl) \
    RDA(a1h, a1l, 1, ((KC) + 1) & 7) \
    QUARTER(2, a2h, a2l, bfh, bfl) \
    RDA(a2h, a2l, 2, ((KC) + 1) & 7) \
    RDA(A3HN, A3LN, 3, ((KC) + 1) & 7) \
    QUARTER(3, A3HC, A3LC, bfh, bfl) \
    __builtin_amdgcn_s_setprio(0); \
} while (0)

__global__ __launch_bounds__(512, 1) void fcm_mfma(const f16* __restrict__ xh,
                                                   const f16* __restrict__ xl,
                                                   const float* __restrict__ diag,
                                                   float* __restrict__ out) {
    __shared__ f16 Ah[TI * NC];          // 32 KB  persistent A hi (swizzled)
    __shared__ f16 Al[TI * NC];          // 32 KB  persistent A lo
    __shared__ f16 Sh[8 * 2048];         // 32 KB  wave-private B hi stripes
    __shared__ f16 Sl[8 * 2048];         // 32 KB  wave-private B lo stripes
    __shared__ float Dall[NN];           // 16 KB  full batch diag
    __shared__ float Scr[TI * 8 * 3];    // 6 KB   cross-wave merge

    const int tid   = threadIdx.x;
    const int bx    = blockIdx.x;
    const int batch = (bx & 7) >> 1;                  // batch -> XCD pair
    const int band  = ((bx >> 3) << 1) | (bx & 1);    // 0..63
    const int i0    = band * TI;

    const f16* __restrict__ xhb = xh + (size_t)batch * NN * NC;
    const f16* __restrict__ xlb = xl + (size_t)batch * NN * NC;
    const float* __restrict__ db = diag + (size_t)batch * NN;

    const int w    = tid >> 6;    // 0..7
    const int lane = tid & 63;
    const int quad = lane >> 4;
    const int l15  = lane & 15;
    const int sw   = l15 & 7;     // A fragment swizzle key

    // wave-private stripe bases
    f16* const swh = Sh + w * 2048;
    f16* const swl = Sl + w * 2048;

    // ---- A stage (once): LDS[row][granule ^ (row&7)] = x[i0+row][granule] ----
    {
        const int rsub = lane >> 5;        // 0/1
        const int s    = lane & 31;
        #pragma unroll
        for (int it = 0; it < 4; ++it) {
            const int t  = w * 4 + it;     // 0..31, 2 rows each
            const int rg = t * 2 + rsub;
            const int g  = s ^ (rg & 7);
            const size_t goff = (size_t)(i0 + rg) * NC + g * 8;
            gl_lds16(xhb + goff, Ah + t * 512);
            gl_lds16(xlb + goff, Al + t * 512);
        }
    }
    // ---- diag stage (once): PER-LANE global source (r7 bug-fix) ----
    #pragma unroll
    for (int t = 0; t < 2; ++t) {
        const int seg = (w * 2 + t) * 256;         // 256 floats per wave-instr
        gl_lds16(db + seg + lane * 4, Dall + seg);
    }

    // B staging lane constants (16 cols x 4 granules per 1KB wave-instr)
    const int bcol  = lane >> 2;                       // col within 16-col group
    const int bslot = (lane & 3) ^ ((lane >> 3) & 3);  // source granule for this slot
    const int gB    = (quad ^ ((l15 >> 1) & 3)) * 8;   // B frag read granule (const)

    // ---- prologue: stage stripe for chunk 0 (jt=0,kc=0) ----
    #pragma unroll
    for (int t = 0; t < 4; ++t) {
        const size_t goff = (size_t)(w * 64 + t * 16 + bcol) * NC + bslot * 8;
        gl_lds16(xhb + goff, swh + t * 512);
        gl_lds16(xlb + goff, swl + t * 512);
    }
    __syncthreads();      // drains A + diag + stripe0; only barrier before epilogue

    // frag registers: a0..a2 rotate in place; a3 ping-pongs (A/B); bf re-read
    // each chunk (single set — consumed and reloaded within the chunk)
    f16x8 a0h, a0l, a1h, a1l, a2h, a2l, a3hA, a3lA, a3hB, a3lB;
    f16x8 bfh[4], bfl[4];

    // preload chunk-0 A frags (drained by CHUNK(0)'s lgkmcnt(0))
    RDA(a0h, a0l, 0, 0) RDA(a1h, a1l, 1, 0) RDA(a2h, a2l, 2, 0) RDA(a3hA, a3lA, 3, 0)

    // running top-2 (+argmin) for the lane's 16 row-slots (rt*4 + p)
    float m1[16], m2[16]; int i1[16];
    #pragma unroll
    for (int r = 0; r < 16; ++r) { m1[r] = FLT_MAX; m2[r] = FLT_MAX; i1[r] = 0x7fffffff; }

    for (int jt = 0; jt < NJT; ++jt) {
        f32x4 acc[4][4];
        #pragma unroll
        for (int rt = 0; rt < 4; ++rt)
            #pragma unroll
            for (int ct = 0; ct < 4; ++ct)
                acc[rt][ct] = (f32x4){0.f, 0.f, 0.f, 0.f};

        CHUNK(0, a3hA, a3lA, a3hB, a3lB);
        CHUNK(1, a3hB, a3lB, a3hA, a3lA);
        CHUNK(2, a3hA, a3lA, a3hB, a3lB);
        CHUNK(3, a3hB, a3lB, a3hA, a3lA);
        CHUNK(4, a3hA, a3lA, a3hB, a3lB);
        CHUNK(5, a3hB, a3lB, a3hA, a3lA);
        CHUNK(6, a3hA, a3lA, a3hB, a3lB);
        CHUNK(7, a3hB, a3lB, a3hA, a3lA);

        // fold j-tile into running top-2; key = diag_j - 2*dot (monotone in dist)
        #pragma unroll
        for (int ct = 0; ct < 4; ++ct) {
            const int col = jt * TJ + w * 64 + ct * 16 + l15;
            const float dj = Dall[col];                // LDS broadcast read
            #pragma unroll
            for (int rt = 0; rt < 4; ++rt) {
                #pragma unroll
                for (int p = 0; p < 4; ++p) {
                    const int rglob = i0 + rt * 16 + quad * 4 + p;
                    float v = fmaf(-2.0f, acc[rt][ct][p], dj);
                    v = (col == rglob) ? FLT_MAX : v;       // mask self
                    const int slot = rt * 4 + p;
                    const bool lt = v < m1[slot];           // strict: keep earliest j
                    m2[slot] = fminf(m2[slot], fmaxf(m1[slot], v));
                    m1[slot] = fminf(m1[slot], v);
                    i1[slot] = lt ? col : i1[slot];
                }
            }
        }
    }

    // butterfly merge across the 16 col-lanes (l15) holding the same rows
    #pragma unroll
    for (int s = 0; s < 16; ++s) {
        float a1 = m1[s], a2 = m2[s]; int ai = i1[s];
        #pragma unroll
        for (int msk = 1; msk < 16; msk <<= 1) {
            const float o1 = __shfl_xor(a1, msk, 64);
            const float o2 = __shfl_xor(a2, msk, 64);
            const int   oi = __shfl_xor(ai, msk, 64);
            const bool take = (o1 < a1) || (o1 == a1 && oi < ai);
            const float keep = take ? a1 : o1;
            a2 = fminf(fminf(a2, o2), keep);
            a1 = take ? o1 : a1;
            ai = take ? oi : ai;
        }
        m1[s] = a1; m2[s] = a2; i1[s] = ai;
    }
    if (l15 == 0) {
        #pragma unroll
        for (int s = 0; s < 16; ++s) {
            const int rloc = (s >> 2) * 16 + quad * 4 + (s & 3);
            float* p = &Scr[(rloc * 8 + w) * 3];
            p[0] = m1[s]; p[1] = __int_as_float(i1[s]); p[2] = m2[s];
        }
    }
    __syncthreads();
    if (tid < TI) {
        float M1 = FLT_MAX, M2 = FLT_MAX; int I1 = 0x7fffffff;
        #pragma unroll
        for (int t = 0; t < 8; ++t) {
            const float* p = &Scr[(tid * 8 + t) * 3];
            const float o1 = p[0]; const int oi = __float_as_int(p[1]); const float o2 = p[2];
            const bool take = (o1 < M1) || (o1 == M1 && oi < I1);
            const float keep = take ? M1 : o1;
            M2 = fminf(fminf(M2, o2), keep);
            M1 = take ? o1 : M1;
            I1 = take ? oi : I1;
        }
        const int   gi = i0 + tid;
        const float di = Dall[gi];
        const float d1 = sqrtf(fmaxf(di + M1, 0.0f) + 1e-9f);
        const float d2 = sqrtf(fmaxf(di + M2, 0.0f) + 1e-9f);
        const float e  = expf(d1);
        const float pred = (d1 / d2 < 0.6f) ? 2.0f / (1.0f + e)
                                            : 2.0f / (1.0f + 2.0f * e);
        out[(size_t)batch * NN + gi] = pred;
        out[(size_t)NB * NN + (size_t)batch * NN + gi] = (float)I1;
    }
}

// ---------------- fp32 fallback (round-1, passed) if ws too small ----------------
__global__ __launch_bounds__(256) void diag_kernel(const float* __restrict__ x,
                                                   float* __restrict__ diag) {
    const int lane = threadIdx.x & 63;
    const int wave = threadIdx.x >> 6;
    const int row  = (blockIdx.x << 2) + wave;
    const float4 v = ((const float4*)(x + (size_t)row * NC))[lane];
    float s = v.x * v.x + v.y * v.y + v.z * v.z + v.w * v.w;
    #pragma unroll
    for (int off = 32; off; off >>= 1) s += __shfl_xor(s, off, 64);
    if (lane == 0) diag[row] = s;
}

#define FTI 64
#define FTJ 256
#define FKC 16

__global__ __launch_bounds__(256) void fcm_fallback(const float* __restrict__ x,
                                                    const float* __restrict__ diag,
                                                    float* __restrict__ out) {
    __shared__ float As[FKC * FTI];
    __shared__ float Bs[FKC * FTJ];
    __shared__ float Dsf[FTJ];
    __shared__ float Scrf[FTI * 32 * 3];

    const int tid = threadIdx.x;
    const int bx  = blockIdx.x;
    const int batch = (bx & 7) >> 1;
    const int tile  = ((bx >> 3) << 1) | (bx & 1);
    const int i0    = tile * FTI;
    const float* __restrict__ xb = x + (size_t)batch * NN * NC;
    const float* __restrict__ db = diag + (size_t)batch * NN;
    const int tx = tid & 31;
    const int ty = tid >> 5;
    const int sr  = tid & 63;
    const int sk0 = (tid >> 6) << 2;

    float m1[8], m2[8]; int i1[8];
    #pragma unroll
    for (int r = 0; r < 8; ++r) { m1[r] = FLT_MAX; m2[r] = FLT_MAX; i1[r] = 0; }

    for (int jt = 0; jt < NN / FTJ; ++jt) {
        const int j0 = jt * FTJ;
        __syncthreads();
        Dsf[tid] = db[j0 + tid];
        float acc[8][8];
        #pragma unroll
        for (int r = 0; r < 8; ++r)
            #pragma unroll
            for (int c = 0; c < 8; ++c) acc[r][c] = 0.0f;
        float4 pa  = *(const float4*)(xb + (size_t)(i0 + sr) * NC + sk0);
        const float* bsrc = xb + (size_t)(j0 + tid) * NC;
        float4 pb0 = *(const float4*)(bsrc + 0);
        float4 pb1 = *(const float4*)(bsrc + 4);
        float4 pb2 = *(const float4*)(bsrc + 8);
        float4 pb3 = *(const float4*)(bsrc + 12);
        for (int kc = 0; kc < NC / FKC; ++kc) {
            __syncthreads();
            As[(sk0 + 0) * FTI + sr] = pa.x;
            As[(sk0 + 1) * FTI + sr] = pa.y;
            As[(sk0 + 2) * FTI + sr] = pa.z;
            As[(sk0 + 3) * FTI + sr] = pa.w;
            Bs[ 0 * FTJ + tid] = pb0.x; Bs[ 1 * FTJ + tid] = pb0.y;
            Bs[ 2 * FTJ + tid] = pb0.z; Bs[ 3 * FTJ + tid] = pb0.w;
            Bs[ 4 * FTJ + tid] = pb1.x; Bs[ 5 * FTJ + tid] = pb1.y;
            Bs[ 6 * FTJ + tid] = pb1.z; Bs[ 7 * FTJ + tid] = pb1.w;
            Bs[ 8 * FTJ + tid] = pb2.x; Bs[ 9 * FTJ + tid] = pb2.y;
            Bs[10 * FTJ + tid] = pb2.z; Bs[11 * FTJ + tid] = pb2.w;
            Bs[12 * FTJ + tid] = pb3.x; Bs[13 * FTJ + tid] = pb3.y;
            Bs[14 * FTJ + tid] = pb3.z; Bs[15 * FTJ + tid] = pb3.w;
            if (kc + 1 < NC / FKC) {
                const int kb = (kc + 1) * FKC;
                pa  = *(const float4*)(xb + (size_t)(i0 + sr) * NC + kb + sk0);
                pb0 = *(const float4*)(bsrc + kb + 0);
                pb1 = *(const float4*)(bsrc + kb + 4);
                pb2 = *(const float4*)(bsrc + kb + 8);
                pb3 = *(const float4*)(bsrc + kb + 12);
            }
            __syncthreads();
            #pragma unroll
            for (int k = 0; k < FKC; ++k) {
                float av[8], bv[8];
                *(float4*)&av[0] = *(const float4*)&As[k * FTI + ty * 8];
                *(float4*)&av[4] = *(const float4*)&As[k * FTI + ty * 8 + 4];
                *(float4*)&bv[0] = *(const float4*)&Bs[k * FTJ + tx * 8];
                *(float4*)&bv[4] = *(const float4*)&Bs[k * FTJ + tx * 8 + 4];
                #pragma unroll
                for (int r = 0; r < 8; ++r)
                    #pragma unroll
                    for (int c = 0; c < 8; ++c)
                        acc[r][c] = fmaf(av[r], bv[c], acc[r][c]);
            }
        }
        #pragma unroll
        for (int c = 0; c < 8; ++c) {
            const int j = j0 + tx * 8 + c;
            const float dj = Dsf[tx * 8 + c];
            #pragma unroll
            for (int r = 0; r < 8; ++r) {
                const int ig = i0 + ty * 8 + r;
                float v = fmaf(-2.0f, acc[r][c], dj);
                v = (j == ig) ? FLT_MAX : v;
                const bool lt = v < m1[r];
                m2[r] = fminf(m2[r], fmaxf(m1[r], v));
                m1[r] = fminf(m1[r], v);
                i1[r] = lt ? j : i1[r];
            }
        }
    }
    __syncthreads();
    #pragma unroll
    for (int r = 0; r < 8; ++r) {
        float* s = &Scrf[((ty * 8 + r) * 32 + tx) * 3];
        s[0] = m1[r]; s[1] = __int_as_float(i1[r]); s[2] = m2[r];
    }
    __syncthreads();
    if (tid < FTI) {
        float M1 = FLT_MAX, M2 = FLT_MAX; int I1 = 0;
        for (int t = 0; t < 32; ++t) {
            const float* s = &Scrf[(tid * 32 + t) * 3];
            const float v1 = s[0]; const int ii = __float_as_int(s[1]);
            const float v2 = s[2];
            if (v1 < M1 || (v1 == M1 && ii < I1)) {
                M2 = fminf(M2, M1); M1 = v1; I1 = ii;
            } else {
                M2 = fminf(M2, v1);
            }
            M2 = fminf(M2, v2);
        }
        const int   gi = i0 + tid;
        const float di = db[gi];
        const float d1 = sqrtf(fmaxf(di + M1, 0.0f) + 1e-9f);
        const float d2 = sqrtf(fmaxf(di + M2, 0.0f) + 1e-9f);
        const float e  = expf(d1);
        const float pred = (d1 / d2 < 0.6f) ? 2.0f / (1.0f + e)
                                            : 2.0f / (1.0f + 2.0f * e);
        out[(size_t)batch * NN + gi] = pred;
        out[(size_t)NB * NN + (size_t)batch * NN + gi] = (float)I1;
    }
}

extern "C" void kernel_launch(void* const* d_in, const int* in_sizes, int n_in,
                              void* d_out, int out_size, void* d_ws, size_t ws_size,
                              hipStream_t stream) {
    const float* x = (const float*)d_in[0];
    float* out     = (float*)d_out;
    const size_t n_elem = (size_t)NB * NN * NC;
    const size_t need   = n_elem * 2 * 2 + (size_t)NB * NN * 4;   // hi+lo f16 + diag
    if (ws_size >= need) {
        f16*   xh   = (f16*)d_ws;
        f16*   xl   = xh + n_elem;
        float* diag = (float*)(xl + n_elem);
        prep_kernel<<<dim3(NB * NN / 4), dim3(256), 0, stream>>>(x, xh, xl, diag);
        fcm_mfma<<<dim3(256), dim3(512), 0, stream>>>(xh, xl, diag, out);
    } else {
        float* diag = (float*)d_ws;
        diag_kernel<<<dim3(NB * NN / 4), dim3(256), 0, stream>>>(x, diag);
        fcm_fallback<<<dim3(256), dim3(256), 0, stream>>>(x, diag, out);
    }
}

// Round 14
// 166.942 us; speedup vs baseline: 1.0240x; 1.0240x over previous
//
#include <hip/hip_runtime.h>
#include <cfloat>

#define NB 4
#define NN 4096
#define NC 256

typedef _Float16 f16;
typedef _Float16 f16x8 __attribute__((ext_vector_type(8)));
typedef float f32x4 __attribute__((ext_vector_type(4)));

__device__ __forceinline__ void gl_lds16(const void* g, void* l) {
    __builtin_amdgcn_global_load_lds(
        (const __attribute__((address_space(1))) unsigned int*)g,
        (__attribute__((address_space(3))) unsigned int*)l, 16, 0, 0);
}

// ---------------- prep: fp32 -> f16 hi/lo split + diag ----------------
__global__ __launch_bounds__(256) void prep_kernel(const float* __restrict__ x,
                                                   f16* __restrict__ xh,
                                                   f16* __restrict__ xl,
                                                   float* __restrict__ diag) {
    const int lane = threadIdx.x & 63;
    const int wave = threadIdx.x >> 6;
    const int row  = (blockIdx.x << 2) + wave;            // 0..16383
    const float4 v = ((const float4*)(x + (size_t)row * NC))[lane];
    union { f16 h[4]; uint2 u; } H, L;
    float vv[4] = {v.x, v.y, v.z, v.w};
    float s = 0.f;
    #pragma unroll
    for (int k = 0; k < 4; ++k) {
        H.h[k] = (f16)vv[k];
        L.h[k] = (f16)(vv[k] - (float)H.h[k]);
        s = fmaf(vv[k], vv[k], s);
    }
    *(uint2*)(xh + (size_t)row * NC + lane * 4) = H.u;
    *(uint2*)(xl + (size_t)row * NC + lane * 4) = L.u;
    #pragma unroll
    for (int off = 32; off; off >>= 1) s += __shfl_xor(s, off, 64);
    if (lane == 0) diag[row] = s;
}

// ---------------- main MFMA kernel (r8 — session best, LOCKED IN) ----------------
// Fat-wave pipeline: 256 threads (4 waves), __launch_bounds__(256,1) ->
// 1 wave/SIMD. B stripes double-buffered via global_load_lds DMA, counted
// vmcnt(8) (in-order; exactly our 8 in-loop DMAs/chunk -> exact by
// construction). Order-independent lgkmcnt(0) top guard (all frag reads
// issue >= 1 MFMA-quarter before it). A-slot 3 ping-pongs (Q2 load vs Q3
// consume WAR). Diag staged once with PER-LANE global source (the r6/r7
// failure was a lane-uniform source — global_load_lds scatters lane*16B on
// the LDS side but the GLOBAL side is per-lane).
// PLATEAU EVIDENCE (rounds 4-13): five structurally distinct schedules land
// 106-110us — r4 barrier-free 2-wave drift (106), r8 this (107), r13
// r4+r8 hybrid at 2 waves/SIMD + setprio (107.5); refuted levers: exposed
// staging latency (r0=r1), LDS-port byte reduction (r3 +26%, r11 -35%),
// read spreading (r10 -10%), SB removal + VALU diet (r12 +3), A-in-regs
// (r5/r9: arch-VGPR cap 256 -> spill). MfmaUtil pinned 42-45%, HBM 2%:
// a multi-resource additive wall (MFMA + fold VALU + LDS chains), not a
// pipe roofline. Next real lever would be symmetric-D (halve MFMA+fold via
// triangular tile jobs + cross-block partial top-2 merge) — a full rewrite.
#define TI 64
#define TJ 256
#define KCB 32
#define NCHUNK (NC / KCB)    // 8 k-chunks per j-tile
#define NJT (NN / TJ)        // 16 j-tiles

#define TRIPLE(RT, CT, AH, AL, BH, BL) \
    acc[RT][CT] = __builtin_amdgcn_mfma_f32_16x16x32_f16(AH, BH[CT], acc[RT][CT], 0, 0, 0); \
    acc[RT][CT] = __builtin_amdgcn_mfma_f32_16x16x32_f16(AH, BL[CT], acc[RT][CT], 0, 0, 0); \
    acc[RT][CT] = __builtin_amdgcn_mfma_f32_16x16x32_f16(AL, BH[CT], acc[RT][CT], 0, 0, 0);

#define QUARTER(RT, AH, AL, BH, BL) \
    TRIPLE(RT, 0, AH, AL, BH, BL) TRIPLE(RT, 1, AH, AL, BH, BL) \
    TRIPLE(RT, 2, AH, AL, BH, BL) TRIPLE(RT, 3, AH, AL, BH, BL)

// A-frag read for k-chunk KN, row-block RT, into named regs (Ah layout:
// slot g holds granule g ^ (row&7))
#define RDA(DH, DL, RT, KN) \
    DH = *(const f16x8*)&Ah[((RT) * 16 + l15) * NC + ((((KN) * 4 + quad) ^ sw) * 8)]; \
    DL = *(const f16x8*)&Al[((RT) * 16 + l15) * NC + ((((KN) * 4 + quad) ^ sw) * 8)];

#define SB __builtin_amdgcn_sched_barrier(0)

// One k-chunk (KC literal 0..7). All frags for chunk KC were loaded during
// chunk KC-1. Top: lgkmcnt(0) (order-independent, ~free), then DMA chunk
// KC+2 into the buffer chunk KC was read from. Q2: vmcnt(8) = chunk KC+1's
// DMAs retired (KC+2's 8 may fly), read all chunk-KC+1 frags.
#define CHUNK(KC, BHC, BLC, BHN, BLN, A3HC, A3LC, A3HN, A3LN) do { \
    asm volatile("s_waitcnt lgkmcnt(0)" ::: "memory"); \
    SB; \
    { \
        int jn = jt + (((KC) + 2) >> 3); if (jn >= NJT) jn = 0;   /* wrap: dummy stage */ \
        const int kn = ((KC) + 2) & 7; \
        f16* const dh = &Sh[(KC) & 1][w * 2048]; \
        f16* const dl = &Sl[(KC) & 1][w * 2048]; \
        _Pragma("unroll") \
        for (int t = 0; t < 4; ++t) { \
            const int col = jn * TJ + w * 64 + t * 16 + bcol; \
            const size_t goff = (size_t)col * NC + (size_t)(kn * KCB) + bslot * 8; \
            gl_lds16(xhb + goff, dh + t * 512); \
            gl_lds16(xlb + goff, dl + t * 512); \
        } \
    } \
    SB; \
    QUARTER(0, a0h, a0l, BHC, BLC) \
    RDA(a0h, a0l, 0, ((KC) + 1) & 7) \
    SB; \
    QUARTER(1, a1h, a1l, BHC, BLC) \
    RDA(a1h, a1l, 1, ((KC) + 1) & 7) \
    SB; \
    QUARTER(2, a2h, a2l, BHC, BLC) \
    asm volatile("s_waitcnt vmcnt(8)" ::: "memory"); \
    SB; \
    { \
        const f16* const rh = &Sh[((KC) + 1) & 1][w * 2048]; \
        const f16* const rl = &Sl[((KC) + 1) & 1][w * 2048]; \
        _Pragma("unroll") \
        for (int ct = 0; ct < 4; ++ct) { \
            const int c = ct * 16 + l15; \
            BHN[ct] = *(const f16x8*)&rh[c * KCB + gB]; \
            BLN[ct] = *(const f16x8*)&rl[c * KCB + gB]; \
        } \
    } \
    RDA(a2h, a2l, 2, ((KC) + 1) & 7) \
    RDA(A3HN, A3LN, 3, ((KC) + 1) & 7) \
    SB; \
    QUARTER(3, A3HC, A3LC, BHC, BLC) \
} while (0)

__global__ __launch_bounds__(256, 1) void fcm_mfma(const f16* __restrict__ xh,
                                                   const f16* __restrict__ xl,
                                                   const float* __restrict__ diag,
                                                   float* __restrict__ out) {
    __shared__ f16 Ah[TI * NC];          // 32 KB  persistent A hi (swizzled)
    __shared__ f16 Al[TI * NC];          // 32 KB  persistent A lo
    __shared__ f16 Sh[2][4 * 2048];      // 32 KB  B hi stripes, double-buffered
    __shared__ f16 Sl[2][4 * 2048];      // 32 KB  B lo stripes, double-buffered
    __shared__ float Dall[NN];           // 16 KB  full batch diag
    __shared__ float Scr[TI * 4 * 3];    // 3 KB   cross-wave merge

    const int tid   = threadIdx.x;
    const int bx    = blockIdx.x;
    const int batch = (bx & 7) >> 1;                  // batch -> XCD pair
    const int band  = ((bx >> 3) << 1) | (bx & 1);    // 0..63
    const int i0    = band * TI;

    const f16* __restrict__ xhb = xh + (size_t)batch * NN * NC;
    const f16* __restrict__ xlb = xl + (size_t)batch * NN * NC;
    const float* __restrict__ db = diag + (size_t)batch * NN;

    const int w    = tid >> 6;    // 0..3
    const int lane = tid & 63;
    const int quad = lane >> 4;
    const int l15  = lane & 15;
    const int sw   = l15 & 7;     // A fragment swizzle key

    // ---- A stage (once): LDS[row][granule ^ (row&7)] = x[i0+row][granule] ----
    {
        const int rsub = lane >> 5;        // 0/1
        const int s    = lane & 31;
        #pragma unroll
        for (int it = 0; it < 8; ++it) {
            const int t  = w * 8 + it;     // 0..31, 2 rows each
            const int rg = t * 2 + rsub;
            const int g  = s ^ (rg & 7);
            const size_t goff = (size_t)(i0 + rg) * NC + g * 8;
            gl_lds16(xhb + goff, Ah + t * 512);
            gl_lds16(xlb + goff, Al + t * 512);
        }
    }
    // ---- diag stage (once): PER-LANE global source (r7 bug-fix) ----
    #pragma unroll
    for (int t = 0; t < 4; ++t) {
        const int seg = (w * 4 + t) * 256;         // 256 floats per wave-instr
        gl_lds16(db + seg + lane * 4, Dall + seg);
    }

    // B staging lane constants (16 cols x 4 granules per 1KB wave-instr)
    const int bcol  = lane >> 2;                       // col within 16-col group
    const int bslot = (lane & 3) ^ ((lane >> 3) & 3);  // source granule for this slot
    const int gB    = (quad ^ ((l15 >> 1) & 3)) * 8;   // B frag read granule (const)

    // ---- prologue: stage chunk 0 -> buf0, chunk 1 -> buf1 ----
    #pragma unroll
    for (int t = 0; t < 4; ++t) {
        const int col = w * 64 + t * 16 + bcol;
        gl_lds16(xhb + (size_t)col * NC + bslot * 8, &Sh[0][w * 2048] + t * 512);
        gl_lds16(xlb + (size_t)col * NC + bslot * 8, &Sl[0][w * 2048] + t * 512);
    }
    #pragma unroll
    for (int t = 0; t < 4; ++t) {
        const int col = w * 64 + t * 16 + bcol;
        gl_lds16(xhb + (size_t)col * NC + KCB + bslot * 8, &Sh[1][w * 2048] + t * 512);
        gl_lds16(xlb + (size_t)col * NC + KCB + bslot * 8, &Sl[1][w * 2048] + t * 512);
    }
    __syncthreads();      // drains A + diag + chunk0/1; only barrier before epilogue

    // frag registers: a0..a2 rotate in place; a3 ping-pongs (A/B);
    // bf ping-pongs (chunk KC in b{A,B} by parity)
    f16x8 a0h, a0l, a1h, a1l, a2h, a2l, a3hA, a3lA, a3hB, a3lB;
    f16x8 bAh[4], bAl[4], bBh[4], bBl[4];

    // preload chunk-0 frags, then drain lgkm once
    #pragma unroll
    for (int ct = 0; ct < 4; ++ct) {
        const int c = ct * 16 + l15;
        bAh[ct] = *(const f16x8*)&Sh[0][w * 2048 + c * KCB + gB];
        bAl[ct] = *(const f16x8*)&Sl[0][w * 2048 + c * KCB + gB];
    }
    RDA(a0h, a0l, 0, 0) RDA(a1h, a1l, 1, 0) RDA(a2h, a2l, 2, 0) RDA(a3hA, a3lA, 3, 0)
    asm volatile("s_waitcnt lgkmcnt(0)" ::: "memory");
    SB;

    // running top-2 (+argmin) for the lane's 16 row-slots (rt*4 + p)
    float m1[16], m2[16]; int i1[16];
    #pragma unroll
    for (int r = 0; r < 16; ++r) { m1[r] = FLT_MAX; m2[r] = FLT_MAX; i1[r] = 0x7fffffff; }

    for (int jt = 0; jt < NJT; ++jt) {
        f32x4 acc[4][4];
        #pragma unroll
        for (int rt = 0; rt < 4; ++rt)
            #pragma unroll
            for (int ct = 0; ct < 4; ++ct)
                acc[rt][ct] = (f32x4){0.f, 0.f, 0.f, 0.f};

        CHUNK(0, bAh, bAl, bBh, bBl, a3hA, a3lA, a3hB, a3lB);
        CHUNK(1, bBh, bBl, bAh, bAl, a3hB, a3lB, a3hA, a3lA);
        CHUNK(2, bAh, bAl, bBh, bBl, a3hA, a3lA, a3hB, a3lB);
        CHUNK(3, bBh, bBl, bAh, bAl, a3hB, a3lB, a3hA, a3lA);
        CHUNK(4, bAh, bAl, bBh, bBl, a3hA, a3lA, a3hB, a3lB);
        CHUNK(5, bBh, bBl, bAh, bAl, a3hB, a3lB, a3hA, a3lA);
        CHUNK(6, bAh, bAl, bBh, bBl, a3hA, a3lA, a3hB, a3lB);
        CHUNK(7, bBh, bBl, bAh, bAl, a3hB, a3lB, a3hA, a3lA);

        // fold j-tile into running top-2; key = diag_j - 2*dot (monotone in dist)
        #pragma unroll
        for (int ct = 0; ct < 4; ++ct) {
            const int col = jt * TJ + w * 64 + ct * 16 + l15;
            const float dj = Dall[col];                // LDS broadcast read
            #pragma unroll
            for (int rt = 0; rt < 4; ++rt) {
                #pragma unroll
                for (int p = 0; p < 4; ++p) {
                    const int rglob = i0 + rt * 16 + quad * 4 + p;
                    float v = fmaf(-2.0f, acc[rt][ct][p], dj);
                    v = (col == rglob) ? FLT_MAX : v;       // mask self
                    const int slot = rt * 4 + p;
                    const bool lt = v < m1[slot];           // strict: keep earliest j
                    m2[slot] = fminf(m2[slot], fmaxf(m1[slot], v));
                    m1[slot] = fminf(m1[slot], v);
                    i1[slot] = lt ? col : i1[slot];
                }
            }
        }
    }

    // butterfly merge across the 16 col-lanes (l15) holding the same rows
    #pragma unroll
    for (int s = 0; s < 16; ++s) {
        float a1 = m1[s], a2 = m2[s]; int ai = i1[s];
        #pragma unroll
        for (int msk = 1; msk < 16; msk <<= 1) {
            const float o1 = __shfl_xor(a1, msk, 64);
            const float o2 = __shfl_xor(a2, msk, 64);
            const int   oi = __shfl_xor(ai, msk, 64);
            const bool take = (o1 < a1) || (o1 == a1 && oi < ai);
            const float keep = take ? a1 : o1;
            a2 = fminf(fminf(a2, o2), keep);
            a1 = take ? o1 : a1;
            ai = take ? oi : ai;
        }
        m1[s] = a1; m2[s] = a2; i1[s] = ai;
    }
    if (l15 == 0) {
        #pragma unroll
        for (int s = 0; s < 16; ++s) {
            const int rloc = (s >> 2) * 16 + quad * 4 + (s & 3);
            float* p = &Scr[(rloc * 4 + w) * 3];
            p[0] = m1[s]; p[1] = __int_as_float(i1[s]); p[2] = m2[s];
        }
    }
    __syncthreads();
    if (tid < TI) {
        float M1 = FLT_MAX, M2 = FLT_MAX; int I1 = 0x7fffffff;
        #pragma unroll
        for (int t = 0; t < 4; ++t) {
            const float* p = &Scr[(tid * 4 + t) * 3];
            const float o1 = p[0]; const int oi = __float_as_int(p[1]); const float o2 = p[2];
            const bool take = (o1 < M1) || (o1 == M1 && oi < I1);
            const float keep = take ? M1 : o1;
            M2 = fminf(fminf(M2, o2), keep);
            M1 = take ? o1 : M1;
            I1 = take ? oi : I1;
        }
        const int   gi = i0 + tid;
        const float di = Dall[gi];
        const float d1 = sqrtf(fmaxf(di + M1, 0.0f) + 1e-9f);
        const float d2 = sqrtf(fmaxf(di + M2, 0.0f) + 1e-9f);
        const float e  = expf(d1);
        const float pred = (d1 / d2 < 0.6f) ? 2.0f / (1.0f + e)
                                            : 2.0f / (1.0f + 2.0f * e);
        out[(size_t)batch * NN + gi] = pred;
        out[(size_t)NB * NN + (size_t)batch * NN + gi] = (float)I1;
    }
}

// ---------------- fp32 fallback (round-1, passed) if ws too small ----------------
__global__ __launch_bounds__(256) void diag_kernel(const float* __restrict__ x,
                                                   float* __restrict__ diag) {
    const int lane = threadIdx.x & 63;
    const int wave = threadIdx.x >> 6;
    const int row  = (blockIdx.x << 2) + wave;
    const float4 v = ((const float4*)(x + (size_t)row * NC))[lane];
    float s = v.x * v.x + v.y * v.y + v.z * v.z + v.w * v.w;
    #pragma unroll
    for (int off = 32; off; off >>= 1) s += __shfl_xor(s, off, 64);
    if (lane == 0) diag[row] = s;
}

#define FTI 64
#define FTJ 256
#define FKC 16

__global__ __launch_bounds__(256) void fcm_fallback(const float* __restrict__ x,
                                                    const float* __restrict__ diag,
                                                    float* __restrict__ out) {
    __shared__ float As[FKC * FTI];
    __shared__ float Bs[FKC * FTJ];
    __shared__ float Dsf[FTJ];
    __shared__ float Scrf[FTI * 32 * 3];

    const int tid = threadIdx.x;
    const int bx  = blockIdx.x;
    const int batch = (bx & 7) >> 1;
    const int tile  = ((bx >> 3) << 1) | (bx & 1);
    const int i0    = tile * FTI;
    const float* __restrict__ xb = x + (size_t)batch * NN * NC;
    const float* __restrict__ db = diag + (size_t)batch * NN;
    const int tx = tid & 31;
    const int ty = tid >> 5;
    const int sr  = tid & 63;
    const int sk0 = (tid >> 6) << 2;

    float m1[8], m2[8]; int i1[8];
    #pragma unroll
    for (int r = 0; r < 8; ++r) { m1[r] = FLT_MAX; m2[r] = FLT_MAX; i1[r] = 0; }

    for (int jt = 0; jt < NN / FTJ; ++jt) {
        const int j0 = jt * FTJ;
        __syncthreads();
        Dsf[tid] = db[j0 + tid];
        float acc[8][8];
        #pragma unroll
        for (int r = 0; r < 8; ++r)
            #pragma unroll
            for (int c = 0; c < 8; ++c) acc[r][c] = 0.0f;
        float4 pa  = *(const float4*)(xb + (size_t)(i0 + sr) * NC + sk0);
        const float* bsrc = xb + (size_t)(j0 + tid) * NC;
        float4 pb0 = *(const float4*)(bsrc + 0);
        float4 pb1 = *(const float4*)(bsrc + 4);
        float4 pb2 = *(const float4*)(bsrc + 8);
        float4 pb3 = *(const float4*)(bsrc + 12);
        for (int kc = 0; kc < NC / FKC; ++kc) {
            __syncthreads();
            As[(sk0 + 0) * FTI + sr] = pa.x;
            As[(sk0 + 1) * FTI + sr] = pa.y;
            As[(sk0 + 2) * FTI + sr] = pa.z;
            As[(sk0 + 3) * FTI + sr] = pa.w;
            Bs[ 0 * FTJ + tid] = pb0.x; Bs[ 1 * FTJ + tid] = pb0.y;
            Bs[ 2 * FTJ + tid] = pb0.z; Bs[ 3 * FTJ + tid] = pb0.w;
            Bs[ 4 * FTJ + tid] = pb1.x; Bs[ 5 * FTJ + tid] = pb1.y;
            Bs[ 6 * FTJ + tid] = pb1.z; Bs[ 7 * FTJ + tid] = pb1.w;
            Bs[ 8 * FTJ + tid] = pb2.x; Bs[ 9 * FTJ + tid] = pb2.y;
            Bs[10 * FTJ + tid] = pb2.z; Bs[11 * FTJ + tid] = pb2.w;
            Bs[12 * FTJ + tid] = pb3.x; Bs[13 * FTJ + tid] = pb3.y;
            Bs[14 * FTJ + tid] = pb3.z; Bs[15 * FTJ + tid] = pb3.w;
            if (kc + 1 < NC / FKC) {
                const int kb = (kc + 1) * FKC;
                pa  = *(const float4*)(xb + (size_t)(i0 + sr) * NC + kb + sk0);
                pb0 = *(const float4*)(bsrc + kb + 0);
                pb1 = *(const float4*)(bsrc + kb + 4);
                pb2 = *(const float4*)(bsrc + kb + 8);
                pb3 = *(const float4*)(bsrc + kb + 12);
            }
            __syncthreads();
            #pragma unroll
            for (int k = 0; k < FKC; ++k) {
                float av[8], bv[8];
                *(float4*)&av[0] = *(const float4*)&As[k * FTI + ty * 8];
                *(float4*)&av[4] = *(const float4*)&As[k * FTI + ty * 8 + 4];
                *(float4*)&bv[0] = *(const float4*)&Bs[k * FTJ + tx * 8];
                *(float4*)&bv[4] = *(const float4*)&Bs[k * FTJ + tx * 8 + 4];
                #pragma unroll
                for (int r = 0; r < 8; ++r)
                    #pragma unroll
                    for (int c = 0; c < 8; ++c)
                        acc[r][c] = fmaf(av[r], bv[c], acc[r][c]);
            }
        }
        #pragma unroll
        for (int c = 0; c < 8; ++c) {
            const int j = j0 + tx * 8 + c;
            const float dj = Dsf[tx * 8 + c];
            #pragma unroll
            for (int r = 0; r < 8; ++r) {
                const int ig = i0 + ty * 8 + r;
                float v = fmaf(-2.0f, acc[r][c], dj);
                v = (j == ig) ? FLT_MAX : v;
                const bool lt = v < m1[r];
                m2[r] = fminf(m2[r], fmaxf(m1[r], v));
                m1[r] = fminf(m1[r], v);
                i1[r] = lt ? j : i1[r];
            }
        }
    }
    __syncthreads();
    #pragma unroll
    for (int r = 0; r < 8; ++r) {
        float* s = &Scrf[((ty * 8 + r) * 32 + tx) * 3];
        s[0] = m1[r]; s[1] = __int_as_float(i1[r]); s[2] = m2[r];
    }
    __syncthreads();
    if (tid < FTI) {
        float M1 = FLT_MAX, M2 = FLT_MAX; int I1 = 0;
        for (int t = 0; t < 32; ++t) {
            const float* s = &Scrf[(tid * 32 + t) * 3];
            const float v1 = s[0]; const int ii = __float_as_int(s[1]);
            const float v2 = s[2];
            if (v1 < M1 || (v1 == M1 && ii < I1)) {
                M2 = fminf(M2, M1); M1 = v1; I1 = ii;
            } else {
                M2 = fminf(M2, v1);
            }
            M2 = fminf(M2, v2);
        }
        const int   gi = i0 + tid;
        const float di = db[gi];
        const float d1 = sqrtf(fmaxf(di + M1, 0.0f) + 1e-9f);
        const float d2 = sqrtf(fmaxf(di + M2, 0.0f) + 1e-9f);
        const float e  = expf(d1);
        const float pred = (d1 / d2 < 0.6f) ? 2.0f / (1.0f + e)
                                            : 2.0f / (1.0f + 2.0f * e);
        out[(size_t)batch * NN + gi] = pred;
        out[(size_t)NB * NN + (size_t)batch * NN + gi] = (float)I1;
    }
}

extern "C" void kernel_launch(void* const* d_in, const int* in_sizes, int n_in,
                              void* d_out, int out_size, void* d_ws, size_t ws_size,
                              hipStream_t stream) {
    const float* x = (const float*)d_in[0];
    float* out     = (float*)d_out;
    const size_t n_elem = (size_t)NB * NN * NC;
    const size_t need   = n_elem * 2 * 2 + (size_t)NB * NN * 4;   // hi+lo f16 + diag
    if (ws_size >= need) {
        f16*   xh   = (f16*)d_ws;
        f16*   xl   = xh + n_elem;
        float* diag = (float*)(xl + n_elem);
        prep_kernel<<<dim3(NB * NN / 4), dim3(256), 0, stream>>>(x, xh, xl, diag);
        fcm_mfma<<<dim3(256), dim3(256), 0, stream>>>(xh, xl, diag, out);
    } else {
        float* diag = (float*)d_ws;
        diag_kernel<<<dim3(NB * NN / 4), dim3(256), 0, stream>>>(x, diag);
        fcm_fallback<<<dim3(256), dim3(256), 0, stream>>>(x, diag, out);
    }
}